// Round 1
// baseline (90.218 us; speedup 1.0000x reference)
//
#include <hip/hip_runtime.h>

// Problem constants
constexpr int   kN  = 4096;
constexpr int   kD  = 256;
constexpr float kNU = 3.0f;
constexpr int   kNB = kN / 128;                // 32 block-rows/cols
constexpr int   kNPairs = kNB * (kNB + 1) / 2; // 528 upper-tri block pairs
// Sampled median from diag tile 0, self-pairs excluded
constexpr unsigned kSample0 = 128u * 128u - 128u;        // 16256
constexpr unsigned kTarget0 = (kSample0 - 1u) / 2u + 1u; // lower median rank

using f32x4 = __attribute__((ext_vector_type(4))) float;

// ---------------------------------------------------------------------------
// K1: per-row norms + coeff + fp32 -> fp8(e4m3) conversion.
// Also zeroes the fused kernel's sync words (ws is poisoned each iter).
// ---------------------------------------------------------------------------
__global__ __launch_bounds__(256) void prep_kernel(
    const float* __restrict__ z, unsigned int* __restrict__ z8,
    float* __restrict__ norms, float* __restrict__ coef,
    unsigned int* __restrict__ sync_flags) {
  if (blockIdx.x == 0 && threadIdx.x == 0) {
    sync_flags[0] = 0u;   // alpha-ready flag
    sync_flags[1] = 0u;   // done counter
  }
  int tid = threadIdx.x;
  int w = tid >> 6, lane = tid & 63;
  int row = blockIdx.x * 4 + w;
  const float4 v = *(const float4*)(z + (size_t)row * kD + lane * 4);

  unsigned p = 0;
  p = __builtin_amdgcn_cvt_pk_fp8_f32(v.x, v.y, p, false);  // bytes 0,1
  p = __builtin_amdgcn_cvt_pk_fp8_f32(v.z, v.w, p, true);   // bytes 2,3
  z8[((size_t)row * kD >> 2) + lane] = p;

  float sq = v.x * v.x + v.y * v.y + v.z * v.z + v.w * v.w;
  for (int off = 32; off > 0; off >>= 1) sq += __shfl_down(sq, off, 64);
  if (lane == 0) {
    norms[row] = sq;
    coef[row] = -(kNU + (float)kD) / (kNU + sq);   // sigma = 1
  }
}

// ---------------------------------------------------------------------------
// fp8 gram tile: 128x128, BK=128 (2 kc iters), global_load_lds staging,
// XOR-swizzled 16B chunks (8 chunks/row), mfma_f32_16x16x32_fp8_fp8.
// LDS: A 16 KB + B 16 KB.
// ---------------------------------------------------------------------------
__device__ __forceinline__ void gram_tile_fp8(
    const unsigned char* __restrict__ z8, int bRow, int bCol, int tid,
    unsigned char* ldsA, unsigned char* ldsB, f32x4 acc[4][4]) {
  int lane = tid & 63, w = tid >> 6;
  int quad = lane >> 4, l15 = lane & 15;
  int waveM = (w >> 1) * 64, waveN = (w & 1) * 64;

  for (int kc = 0; kc < 2; kc++) {
    if (kc) __syncthreads();
#pragma unroll
    for (int s = 0; s < 4; s++) {
      int slot = (w * 4 + s) * 64 + lane;      // 0..1023, 16 B each
      int row = slot >> 3;                     // 8 chunks per 128-B row
      int cp = slot & 7;
      int c = cp ^ (row & 7);                  // logical chunk stored here
      const unsigned char* gA = z8 + (size_t)(bRow + row) * kD + kc * 128 + c * 16;
      const unsigned char* gB = z8 + (size_t)(bCol + row) * kD + kc * 128 + c * 16;
      __builtin_amdgcn_global_load_lds(
          (const __attribute__((address_space(1))) void*)gA,
          (__attribute__((address_space(3))) void*)(ldsA + (size_t)(w * 4 + s) * 1024),
          16, 0, 0);
      __builtin_amdgcn_global_load_lds(
          (const __attribute__((address_space(1))) void*)gB,
          (__attribute__((address_space(3))) void*)(ldsB + (size_t)(w * 4 + s) * 1024),
          16, 0, 0);
    }
    __syncthreads();
#pragma unroll
    for (int ks = 0; ks < 4; ks++) {           // k = kc*128 + ks*32
      int c = ks * 2 + (quad >> 1);
      int intra = (quad & 1) * 8;
      long aL[4], bL[4];
#pragma unroll
      for (int mi = 0; mi < 4; mi++) {
        int row = waveM + mi * 16 + l15;
        int cp = c ^ (row & 7);
        aL[mi] = *(const long*)(ldsA + row * 128 + cp * 16 + intra);
      }
#pragma unroll
      for (int ni = 0; ni < 4; ni++) {
        int row = waveN + ni * 16 + l15;
        int cp = c ^ (row & 7);
        bL[ni] = *(const long*)(ldsB + row * 128 + cp * 16 + intra);
      }
#pragma unroll
      for (int mi = 0; mi < 4; mi++)
#pragma unroll
        for (int ni = 0; ni < 4; ni++)
          acc[mi][ni] = __builtin_amdgcn_mfma_f32_16x16x32_fp8_fp8(
              aL[mi], bL[ni], acc[mi][ni], 0, 0, 0);
    }
  }
}

__device__ __forceinline__ void tri_decode(int b, int& by, int& bx) {
  int t = b; by = 0;
  while (t >= kNB - by) { t -= kNB - by; by++; }
  bx = by + t;
}

// ---------------------------------------------------------------------------
// K2: fused — gram + (block 0: histogram median -> alpha, flag release)
//            + epilogue + last-block finalize. One dispatch.
// Co-residency: launch_bounds(256,4) (<=128 VGPR) + ~35 KB LDS -> 4 blk/CU,
// 1024 slots >= 528, so the flag poll cannot deadlock.
// ---------------------------------------------------------------------------
__global__ __launch_bounds__(256, 4) void fused_kernel(
    const unsigned char* __restrict__ z8, const float* __restrict__ norms,
    const float* __restrict__ coef, float* __restrict__ alpha_p,
    unsigned int* __restrict__ sync_flags, double* __restrict__ partials,
    float* __restrict__ out) {
  __shared__ __align__(16) unsigned char smem[32768];
  __shared__ float nR[128], nC[128], cR[128], cC[128];
  __shared__ double dpart[4];
  __shared__ float alpha_sh;
  __shared__ int isLast;

  const int tid = threadIdx.x;
  const int bid = blockIdx.x;
  int by, bx; tri_decode(bid, by, bx);
  int bRow = by * 128, bCol = bx * 128;
  if (tid < 128) { nR[tid] = norms[bRow + tid]; cR[tid] = coef[bRow + tid]; }
  else { int u = tid - 128; nC[u] = norms[bCol + u]; cC[u] = coef[bCol + u]; }

  const int lane = tid & 63, w = tid >> 6;
  const int quad = lane >> 4, l15 = lane & 15;
  const int waveM = (w >> 1) * 64, waveN = (w & 1) * 64;

  f32x4 acc[4][4] = {};
  gram_tile_fp8(z8, bRow, bCol, tid, smem, smem + 16384, acc);

  // ---- Block 0: histogram median over diag tile 0 (staging LDS is dead now)
  if (bid == 0) {
    __syncthreads();                             // everyone done reading smem
    unsigned int* hist = (unsigned int*)smem;    // overlay 16 KB
    for (int i = tid; i < 4096; i += 256) hist[i] = 0;
    __syncthreads();
#pragma unroll
    for (int mi = 0; mi < 4; mi++) {
      int rl0 = waveM + mi * 16 + quad * 4;
#pragma unroll
      for (int r = 0; r < 4; r++) {
        int rl = rl0 + r;
        float ni_ = nR[rl];
#pragma unroll
        for (int nj = 0; nj < 4; nj++) {
          int cl = waveN + nj * 16 + l15;
          if (rl == cl) continue;
          float g = acc[mi][nj][r];
          float dist = fmaxf(ni_ + nR[cl] - 2.0f * g, 0.0f);
          int bin = (int)(dist * 4.0f);
          bin = bin > 4095 ? 4095 : bin;
          atomicAdd(&hist[bin], 1u);
        }
      }
    }
    __syncthreads();
    if (tid < 64) {
      unsigned own = 0;
#pragma unroll
      for (int u = 0; u < 64; u++) own += hist[tid * 64 + u];
      unsigned incl = own;
#pragma unroll
      for (int off = 1; off < 64; off <<= 1) {
        unsigned t = __shfl_up(incl, off, 64);
        if (tid >= off) incl += t;
      }
      unsigned excl = incl - own;
      unsigned long long bal = __ballot(incl >= kTarget0 && excl < kTarget0);
      int chunk = __ffsll((long long)bal) - 1;
      unsigned exclChunk = __shfl(excl, chunk, 64);
      unsigned h = hist[chunk * 64 + tid];
      unsigned fincl = h;
#pragma unroll
      for (int off = 1; off < 64; off <<= 1) {
        unsigned t = __shfl_up(fincl, off, 64);
        if (tid >= off) fincl += t;
      }
      unsigned long long cum = (unsigned long long)exclChunk + (fincl - h);
      if (cum < kTarget0 && cum + h >= kTarget0) {
        int b = chunk * 64 + tid;
        float frac = (float)(kTarget0 - cum) / (float)h;
        float med = ((float)b + frac) * 0.25f;
        alpha_p[0] = 1.0f / (med + 1e-6f);
      }
    }
    __syncthreads();                             // alpha_p store done (vmcnt drained at barrier)
    if (tid == 0) {
      __threadfence();                           // flush this XCD's L2 (alpha line)
      __hip_atomic_store(&sync_flags[0], 1u, __ATOMIC_RELEASE,
                         __HIP_MEMORY_SCOPE_AGENT);
    }
  }

  // ---- All blocks: wait for alpha (block 0 passes immediately)
  if (tid == 0) {
    while (__hip_atomic_load(&sync_flags[0], __ATOMIC_RELAXED,
                             __HIP_MEMORY_SCOPE_AGENT) == 0u)
      __builtin_amdgcn_s_sleep(1);
    __threadfence();                             // acquire: invalidate stale caches
    alpha_sh = alpha_p[0];
  }
  __syncthreads();

  // ---- Epilogue: k_stein partial (identical math to previous main_kernel)
  const float alpha = alpha_sh;
  const bool diag = (by == bx);
  const float wf = diag ? 1.0f : 2.0f;
  float part = 0.0f;
#pragma unroll
  for (int mi = 0; mi < 4; mi++) {
    int rl0 = waveM + mi * 16 + quad * 4;
#pragma unroll
    for (int r = 0; r < 4; r++) {
      int rl = rl0 + r;
      float ni_ = nR[rl];
      float ci  = cR[rl];
#pragma unroll
      for (int nj = 0; nj < 4; nj++) {
        int cl = waveN + nj * 16 + l15;
        float g = acc[mi][nj][r];
        float njv = nC[cl];
        float cj  = cC[cl];
        float dist = fmaxf(ni_ + njv - 2.0f * g, 0.0f);
        float base = fmaf(alpha, dist, 1.0f);
        float rq  = rsqrtf(base);      // K = base^-0.5
        float rq2 = rq * rq;
        float gc  = -alpha * rq * rq2; // grad_coeff
        float ta  = ci * cj * g * rq;
        float tb  = -gc * ci * (ni_ - g);
        float tc  =  gc * cj * (g - njv);
        float lap =  gc * ((float)kD - 3.0f * alpha * dist * rq2);
        float v = ta + tb + tc + lap;
        if (!(diag && rl == cl)) part += wf * v;
      }
    }
  }

  double d = (double)part;
  for (int off = 32; off > 0; off >>= 1) d += __shfl_down(d, off, 64);
  if (lane == 0) dpart[w] = d;
  __syncthreads();

  // ---- Publish partial; last arriving block finalizes (deterministic order)
  if (tid == 0) {
    partials[bid] = dpart[0] + dpart[1] + dpart[2] + dpart[3];
    __threadfence();                             // release partials to agent scope
    unsigned int old = __hip_atomic_fetch_add(&sync_flags[1], 1u,
                         __ATOMIC_ACQ_REL, __HIP_MEMORY_SCOPE_AGENT);
    isLast = (old == (unsigned)(kNPairs - 1)) ? 1 : 0;
  }
  __syncthreads();

  if (isLast) {
    double s = 0.0;
    for (int i = tid; i < kNPairs; i += 256) s += partials[i];
    for (int off = 32; off > 0; off >>= 1) s += __shfl_down(s, off, 64);
    if (lane == 0) dpart[w] = s;
    __syncthreads();
    if (tid == 0) {
      double tot = dpart[0] + dpart[1] + dpart[2] + dpart[3];
      out[0] = (float)(tot / ((double)kN * (double)(kN - 1)));
    }
  }
}

// ---------------------------------------------------------------------------
extern "C" void kernel_launch(void* const* d_in, const int* in_sizes, int n_in,
                              void* d_out, int out_size, void* d_ws, size_t ws_size,
                              hipStream_t stream) {
  const float* z = (const float*)d_in[0];
  float* out = (float*)d_out;

  char* ws = (char*)d_ws;
  unsigned char* z8 = (unsigned char*)ws;                     // 1 MB fp8
  float* norms = (float*)(ws + (size_t)kN * kD);
  float* coef  = norms + kN;
  float* alpha = coef + kN;
  unsigned int* sync_flags = (unsigned int*)(alpha + 1);      // [0]=flag,[1]=ctr
  double* partials = (double*)(ws + (2 << 20));               // 8-aligned

  prep_kernel<<<kN / 4, 256, 0, stream>>>(z, (unsigned int*)z8, norms, coef,
                                          sync_flags);
  fused_kernel<<<kNPairs, 256, 0, stream>>>(z8, norms, coef, alpha, sync_flags,
                                            partials, out);
}

// Round 2
// 80.021 us; speedup vs baseline: 1.1274x; 1.1274x over previous
//
#include <hip/hip_runtime.h>

// Problem constants
constexpr int   kN  = 4096;
constexpr int   kD  = 256;
constexpr float kNU = 3.0f;
constexpr int   kNB = kN / 128;                // 32 block-rows/cols
constexpr int   kNPairs = kNB * (kNB + 1) / 2; // 528 upper-tri block pairs
// Sampled median from diag tile 0, self-pairs excluded
constexpr unsigned kSample0 = 128u * 128u - 128u;        // 16256
constexpr unsigned kTarget0 = (kSample0 - 1u) / 2u + 1u; // lower median rank

using f32x4 = __attribute__((ext_vector_type(4))) float;

// ---------------------------------------------------------------------------
// K1: per-row norms + coeff + fp32 -> fp8(e4m3) conversion.
// ---------------------------------------------------------------------------
__global__ __launch_bounds__(256) void prep_kernel(
    const float* __restrict__ z, unsigned int* __restrict__ z8,
    float* __restrict__ norms, float* __restrict__ coef) {
  int tid = threadIdx.x;
  int w = tid >> 6, lane = tid & 63;
  int row = blockIdx.x * 4 + w;
  const float4 v = *(const float4*)(z + (size_t)row * kD + lane * 4);

  unsigned p = 0;
  p = __builtin_amdgcn_cvt_pk_fp8_f32(v.x, v.y, p, false);  // bytes 0,1
  p = __builtin_amdgcn_cvt_pk_fp8_f32(v.z, v.w, p, true);   // bytes 2,3
  z8[((size_t)row * kD >> 2) + lane] = p;

  float sq = v.x * v.x + v.y * v.y + v.z * v.z + v.w * v.w;
  for (int off = 32; off > 0; off >>= 1) sq += __shfl_down(sq, off, 64);
  if (lane == 0) {
    norms[row] = sq;
    coef[row] = -(kNU + (float)kD) / (kNU + sq);   // sigma = 1
  }
}

// ---------------------------------------------------------------------------
// fp8 gram tile: 128x128, BK=128 (2 kc iters), global_load_lds staging,
// XOR-swizzled 16B chunks (8 chunks/row), mfma_f32_16x16x32_fp8_fp8.
// SAME=true: A-tile == B-tile (stage once into ldsA, read both ops from it).
// ---------------------------------------------------------------------------
template <bool SAME>
__device__ __forceinline__ void gram_tile_fp8(
    const unsigned char* __restrict__ z8, int bRow, int bCol, int tid,
    unsigned char* ldsA, unsigned char* ldsB, f32x4 acc[4][4]) {
  int lane = tid & 63, w = tid >> 6;
  int quad = lane >> 4, l15 = lane & 15;
  int waveM = (w >> 1) * 64, waveN = (w & 1) * 64;
  const unsigned char* ldsBr = SAME ? ldsA : ldsB;

  for (int kc = 0; kc < 2; kc++) {
    if (kc) __syncthreads();
#pragma unroll
    for (int s = 0; s < 4; s++) {
      int slot = (w * 4 + s) * 64 + lane;      // 0..1023, 16 B each
      int row = slot >> 3;                     // 8 chunks per 128-B row
      int cp = slot & 7;
      int c = cp ^ (row & 7);                  // logical chunk stored here
      const unsigned char* gA = z8 + (size_t)(bRow + row) * kD + kc * 128 + c * 16;
      __builtin_amdgcn_global_load_lds(
          (const __attribute__((address_space(1))) void*)gA,
          (__attribute__((address_space(3))) void*)(ldsA + (size_t)(w * 4 + s) * 1024),
          16, 0, 0);
      if (!SAME) {
        const unsigned char* gB = z8 + (size_t)(bCol + row) * kD + kc * 128 + c * 16;
        __builtin_amdgcn_global_load_lds(
            (const __attribute__((address_space(1))) void*)gB,
            (__attribute__((address_space(3))) void*)(ldsB + (size_t)(w * 4 + s) * 1024),
            16, 0, 0);
      }
    }
    __syncthreads();
#pragma unroll
    for (int ks = 0; ks < 4; ks++) {           // k = kc*128 + ks*32
      int c = ks * 2 + (quad >> 1);
      int intra = (quad & 1) * 8;
      long aL[4], bL[4];
#pragma unroll
      for (int mi = 0; mi < 4; mi++) {
        int row = waveM + mi * 16 + l15;
        int cp = c ^ (row & 7);
        aL[mi] = *(const long*)(ldsA + row * 128 + cp * 16 + intra);
      }
#pragma unroll
      for (int ni = 0; ni < 4; ni++) {
        int row = waveN + ni * 16 + l15;
        int cp = c ^ (row & 7);
        bL[ni] = *(const long*)(ldsBr + row * 128 + cp * 16 + intra);
      }
#pragma unroll
      for (int mi = 0; mi < 4; mi++)
#pragma unroll
        for (int ni = 0; ni < 4; ni++)
          acc[mi][ni] = __builtin_amdgcn_mfma_f32_16x16x32_fp8_fp8(
              aL[mi], bL[ni], acc[mi][ni], 0, 0, 0);
    }
  }
}

__device__ __forceinline__ void tri_decode(int b, int& by, int& bx) {
  int t = b; by = 0;
  while (t >= kNB - by) { t -= kNB - by; by++; }
  bx = by + t;
}

// ---------------------------------------------------------------------------
// K2: main — every block redundantly computes alpha from tile (0,0)
// (bit-identical across blocks: same gram MFMA sequence, integer histogram,
// same scan), then its own tri-pair gram + k_stein epilogue. No cross-block
// sync of any kind; partials consumed by K3 via the dispatch boundary.
// ---------------------------------------------------------------------------
__global__ __launch_bounds__(256, 4) void main_kernel(
    const unsigned char* __restrict__ z8, const float* __restrict__ norms,
    const float* __restrict__ coef, double* __restrict__ partials) {
  __shared__ __align__(16) unsigned char smem[32768];
  __shared__ float nR[128], nC[128], cR[128], cC[128];
  __shared__ float nT[128];
  __shared__ double dpart[4];
  __shared__ float alpha_sh;
  int tid = threadIdx.x;

  int by, bx; tri_decode(blockIdx.x, by, bx);
  int bRow = by * 128, bCol = bx * 128;
  if (tid < 128) { nR[tid] = norms[bRow + tid]; cR[tid] = coef[bRow + tid]; }
  else { int u = tid - 128; nC[u] = norms[bCol + u]; cC[u] = coef[bCol + u]; }
  if (tid < 128) nT[tid] = norms[tid];

  int lane = tid & 63, w = tid >> 6;
  int quad = lane >> 4, l15 = lane & 15;
  int waveM = (w >> 1) * 64, waveN = (w & 1) * 64;

  // ---- Phase A: alpha from tile (0,0). Hist overlays ldsB (unused by SAME
  // gram); zero-writes ordered before binning by gram's internal barriers.
  unsigned int* hist = (unsigned int*)(smem + 16384);
  for (int i = tid; i < 4096; i += 256) hist[i] = 0;

  f32x4 acc[4][4] = {};
  gram_tile_fp8<true>(z8, 0, 0, tid, smem, smem, acc);

#pragma unroll
  for (int mi = 0; mi < 4; mi++) {
    int rl0 = waveM + mi * 16 + quad * 4;
#pragma unroll
    for (int r = 0; r < 4; r++) {
      int rl = rl0 + r;
      float ni_ = nT[rl];
#pragma unroll
      for (int nj = 0; nj < 4; nj++) {
        int cl = waveN + nj * 16 + l15;
        if (rl == cl) continue;
        float g = acc[mi][nj][r];
        float dist = fmaxf(ni_ + nT[cl] - 2.0f * g, 0.0f);
        int bin = (int)(dist * 4.0f);
        bin = bin > 4095 ? 4095 : bin;
        atomicAdd(&hist[bin], 1u);
      }
    }
  }
  __syncthreads();

  if (tid < 64) {
    unsigned own = 0;
#pragma unroll
    for (int u = 0; u < 64; u++) own += hist[tid * 64 + u];
    unsigned incl = own;
#pragma unroll
    for (int off = 1; off < 64; off <<= 1) {
      unsigned t = __shfl_up(incl, off, 64);
      if (tid >= off) incl += t;
    }
    unsigned excl = incl - own;
    unsigned long long bal = __ballot(incl >= kTarget0 && excl < kTarget0);
    int chunk = __ffsll((long long)bal) - 1;
    unsigned exclChunk = __shfl(excl, chunk, 64);
    unsigned h = hist[chunk * 64 + tid];
    unsigned fincl = h;
#pragma unroll
    for (int off = 1; off < 64; off <<= 1) {
      unsigned t = __shfl_up(fincl, off, 64);
      if (tid >= off) fincl += t;
    }
    unsigned long long cum = (unsigned long long)exclChunk + (fincl - h);
    if (cum < kTarget0 && cum + h >= kTarget0) {
      int b = chunk * 64 + tid;
      float frac = (float)(kTarget0 - cum) / (float)h;
      float med = ((float)b + frac) * 0.25f;
      alpha_sh = 1.0f / (med + 1e-6f);
    }
  }
  __syncthreads();         // alpha_sh visible; hist/ldsA dead beyond here
  const float alpha = alpha_sh;

  // ---- Phase B: own-tile gram (reuse acc, re-zeroed)
#pragma unroll
  for (int mi = 0; mi < 4; mi++)
#pragma unroll
    for (int nj = 0; nj < 4; nj++)
#pragma unroll
      for (int k = 0; k < 4; k++) acc[mi][nj][k] = 0.0f;

  gram_tile_fp8<false>(z8, bRow, bCol, tid, smem, smem + 16384, acc);

  // ---- Epilogue: k_stein partial (identical math to round-0 main_kernel)
  const bool diag = (by == bx);
  const float wf = diag ? 1.0f : 2.0f;
  float part = 0.0f;
#pragma unroll
  for (int mi = 0; mi < 4; mi++) {
    int rl0 = waveM + mi * 16 + quad * 4;
#pragma unroll
    for (int r = 0; r < 4; r++) {
      int rl = rl0 + r;
      float ni_ = nR[rl];
      float ci  = cR[rl];
#pragma unroll
      for (int nj = 0; nj < 4; nj++) {
        int cl = waveN + nj * 16 + l15;
        float g = acc[mi][nj][r];
        float njv = nC[cl];
        float cj  = cC[cl];
        float dist = fmaxf(ni_ + njv - 2.0f * g, 0.0f);
        float base = fmaf(alpha, dist, 1.0f);
        float rq  = rsqrtf(base);      // K = base^-0.5
        float rq2 = rq * rq;
        float gc  = -alpha * rq * rq2; // grad_coeff
        float ta  = ci * cj * g * rq;
        float tb  = -gc * ci * (ni_ - g);
        float tc  =  gc * cj * (g - njv);
        float lap =  gc * ((float)kD - 3.0f * alpha * dist * rq2);
        float v = ta + tb + tc + lap;
        if (!(diag && rl == cl)) part += wf * v;
      }
    }
  }

  double d = (double)part;
  for (int off = 32; off > 0; off >>= 1) d += __shfl_down(d, off, 64);
  if (lane == 0) dpart[w] = d;
  __syncthreads();
  if (tid == 0) partials[blockIdx.x] = dpart[0] + dpart[1] + dpart[2] + dpart[3];
}

// ---------------------------------------------------------------------------
// K3: finalize — one block sums 528 partials (deterministic order)
// ---------------------------------------------------------------------------
__global__ __launch_bounds__(256) void finalize_kernel(
    const double* __restrict__ partials, float* __restrict__ out) {
  __shared__ double dpart[4];
  int tid = threadIdx.x;
  int lane = tid & 63, w = tid >> 6;
  double s = 0.0;
  for (int i = tid; i < kNPairs; i += 256) s += partials[i];
  for (int off = 32; off > 0; off >>= 1) s += __shfl_down(s, off, 64);
  if (lane == 0) dpart[w] = s;
  __syncthreads();
  if (tid == 0) {
    double tot = dpart[0] + dpart[1] + dpart[2] + dpart[3];
    out[0] = (float)(tot / ((double)kN * (double)(kN - 1)));
  }
}

// ---------------------------------------------------------------------------
extern "C" void kernel_launch(void* const* d_in, const int* in_sizes, int n_in,
                              void* d_out, int out_size, void* d_ws, size_t ws_size,
                              hipStream_t stream) {
  const float* z = (const float*)d_in[0];
  float* out = (float*)d_out;

  char* ws = (char*)d_ws;
  unsigned char* z8 = (unsigned char*)ws;                     // 1 MB fp8
  float* norms = (float*)(ws + (size_t)kN * kD);
  float* coef  = norms + kN;
  double* partials = (double*)(ws + (2 << 20));               // 8-aligned

  prep_kernel<<<kN / 4, 256, 0, stream>>>(z, (unsigned int*)z8, norms, coef);
  main_kernel<<<kNPairs, 256, 0, stream>>>(z8, norms, coef, partials);
  finalize_kernel<<<1, 256, 0, stream>>>(partials, out);
}